// Round 9
// baseline (231.443 us; speedup 1.0000x reference)
//
#include <hip/hip_runtime.h>

#define NN 50000
#define NE 1250000
#define DD 64
#define KRF 1563      // fine bins of 32 nodes (dst >> 5); 1563*32 = 50016
#define BSH 5         // log2 nodes per bin
#define SCAPF 1024    // staged-edge capacity per bin (mean 800, +8 sigma)
#define SCSHF 10      // log2(SCAPF)
#define NBLK 611      // partition blocks: ceil(NE/4 / 512)

// ---------------------------------------------------------------------------
// ws layout: total[2048] int | Wt[4096] f32 | staging[KRF*SCAPF] u32 (6.4MB)
//            | hist[NBLK*KRF] u16 (1.91MB)
// staging payload = src(16b) | (ef1*8+ef0)(5b)<<16 | (dst&31)(5b)<<21
// R12: atomic-free partition. The ~105us residual was invariant across all
// k_part shapes; the invariant was ~5-7K serialized global-atomic RMWs per
// counter cache line (prefix allocation). Replaced by count -> scan ->
// scatter with exact per-(block,bin) bases: ZERO global atomics, no memset.
// agg reverted byte-exact to R10 (88.9us, VGPR 64); reads total[] now.
// ---------------------------------------------------------------------------

// Pass 1: per-block histogram, dense write (no atomics beyond LDS).
__global__ __launch_bounds__(512) void k_count(
    const int4* __restrict__ dst4, unsigned short* __restrict__ hist,
    const float* __restrict__ W, float* __restrict__ Wt)
{
    __shared__ int hs[KRF];
    const int t  = threadIdx.x;
    const int gb = blockIdx.x;

    for (int i = t; i < KRF; i += 512) hs[i] = 0;
    if (gb == 0)   // piggyback W transpose
        for (int i = t; i < 4096; i += 512)
            Wt[(i & 63) * DD + (i >> 6)] = W[i];
    __syncthreads();

    const int i4 = gb * 512 + t;
    if (i4 < NE / 4) {
        const int4 d = dst4[i4];
        atomicAdd(&hs[d.x >> BSH], 1);
        atomicAdd(&hs[d.y >> BSH], 1);
        atomicAdd(&hs[d.z >> BSH], 1);
        atomicAdd(&hs[d.w >> BSH], 1);
    }
    __syncthreads();

    unsigned short* hrow = hist + (size_t)gb * KRF;
    for (int i = t; i < KRF; i += 512)
        hrow[i] = (unsigned short)hs[i];
}

// Pass 2: per-bin exclusive prefix over blocks (in-place), totals out.
// One thread per bin; lanes cover consecutive bins -> coalesced u16 access.
// 16-way chunked loads for ILP (611 serial L2 hits would be ~75us otherwise).
__global__ __launch_bounds__(256) void k_scan(
    unsigned short* __restrict__ hist, int* __restrict__ total)
{
    const int b = blockIdx.x * 256 + threadIdx.x;
    if (b >= KRF) return;

    int acc = 0;
    for (int g0 = 0; g0 < NBLK; g0 += 16) {
        const int n = min(16, NBLK - g0);
        int hbuf[16];
#pragma unroll
        for (int k = 0; k < 16; ++k)
            if (k < n) hbuf[k] = hist[(size_t)(g0 + k) * KRF + b];
#pragma unroll
        for (int k = 0; k < 16; ++k)
            if (k < n) {
                hist[(size_t)(g0 + k) * KRF + b] =
                    (unsigned short)min(acc, 65535);
                acc += hbuf[k];
            }
    }
    total[b] = acc;
}

// Pass 3: scatter with exact bases; LDS ranks only, no global atomics.
__global__ __launch_bounds__(512) void k_scatter(
    const int4* __restrict__ src4, const int4* __restrict__ dst4,
    const int4* __restrict__ ef04, const int4* __restrict__ ef14,
    const unsigned short* __restrict__ hist, unsigned* __restrict__ staging)
{
    __shared__ int base_s[KRF], cur[KRF];   // 12.5 KB
    const int t  = threadIdx.x;
    const int gb = blockIdx.x;

    const unsigned short* hrow = hist + (size_t)gb * KRF;
    for (int i = t; i < KRF; i += 512) { base_s[i] = hrow[i]; cur[i] = 0; }
    __syncthreads();

    const int i4 = gb * 512 + t;
    if (i4 < NE / 4) {
        const int4 s  = src4[i4], d = dst4[i4];
        const int4 f0 = ef04[i4], f1 = ef14[i4];
        const int ds[4] = {d.x, d.y, d.z, d.w};
        const int ss[4] = {s.x, s.y, s.z, s.w};
        const int a0[4] = {f0.x, f0.y, f0.z, f0.w};
        const int a1[4] = {f1.x, f1.y, f1.z, f1.w};
#pragma unroll
        for (int u = 0; u < 4; ++u) {
            const int bin = ds[u] >> BSH;
            const unsigned pay = (unsigned)ss[u]
                | ((unsigned)(a1[u] * 8 + a0[u]) << 16)
                | ((unsigned)(ds[u] & 31) << 21);
            const int rank = atomicAdd(&cur[bin], 1);
            const int slot = base_s[bin] + rank;
            if (slot < SCAPF) staging[(bin << SCSHF) + slot] = pay;
        }
    }
}

// ---------------------------------------------------------------------------
// Fused bucket + aggregation + MessageNorm + residual + GEMM.
// Byte-exact R10 structure (88.9us, VGPR 64): block = 32 nodes = one bin.
// ---------------------------------------------------------------------------
__global__ __launch_bounds__(256, 4) void genconv_agg(
    const float* __restrict__ nf,
    const float* __restrict__ emb0, const float* __restrict__ emb1,
    const float* __restrict__ Wt,  const float* __restrict__ b,
    const float* __restrict__ beta_p, const float* __restrict__ scale_p,
    const unsigned* __restrict__ staging, const int* __restrict__ total,
    float* __restrict__ out)
{
    __shared__ float emb_s[32 * DD];      // 8 KB
    __shared__ float feat_s[4][DD];       // 1 KB
    __shared__ unsigned buck[32 * DD];    // 8 KB
    __shared__ int ldeg[32];

    const int t    = threadIdx.x;
    const int w    = t >> 6;
    const int lane = t & 63;
    const int bin  = blockIdx.x;
    const int base_node = bin << BSH;

    if (t < 32) ldeg[t] = 0;
    for (int i = t; i < 32 * DD; i += 256) {
        const int rr = i >> 6, c = i & 63;
        emb_s[i] = emb0[(rr & 7) * DD + c] + emb1[(rr >> 3) * DD + c];
    }

    float4 wc[16];
#pragma unroll
    for (int k = 0; k < 16; ++k)
        wc[k] = *(const float4*)(Wt + lane * DD + 4 * k);

    const float bias  = b[lane];
    const float beta  = beta_p[0];
    const float scale = scale_p[0];
    __syncthreads();

    // ---- Phase 1: bucket own segment's edges into per-node LDS lists ----
    const int ne = min(total[bin], SCAPF);
    const unsigned* sg = staging + (bin << SCSHF);
    for (int i = t; i < ne; i += 256) {
        const unsigned p = sg[i];
        const int dl  = (p >> 21) & 31;
        const int pos = atomicAdd(&ldeg[dl], 1);
        if (pos < DD) buck[(dl << 6) + pos] = p & 0x1FFFFFu;
    }
    __syncthreads();

    // ---- Phase 2: 8 nodes per wave, proven scalar-gather loop ----
    const int nl0 = w << 3;
    unsigned pl = buck[(nl0 << 6) + lane];
    int cn = min(ldeg[nl0], DD);
    int node = base_node + nl0;
    float f = (node < NN) ? nf[(size_t)node * DD + lane] : 0.0f;

    for (int i = 0; i < 8; ++i) {
        const int nl = nl0 + i;
        node = base_node + nl;

        // prefetch next node's state (LDS payload + global feature)
        unsigned pl_n = 0u;
        int cn_n = 0;
        float f_n = 0.0f;
        if (i < 7) {
            pl_n = buck[((nl + 1) << 6) + lane];
            cn_n = ldeg[nl + 1];
            if (node + 1 < NN)
                f_n = nf[(size_t)(node + 1) * DD + lane];
        }

        float num = 0.0f, den = 0.0f;
        for (int j = 0; j < cn; j += 16) {
            float a[16];
            unsigned qv[16];
#pragma unroll
            for (int u = 0; u < 16; ++u) {
                const unsigned qq =
                    (unsigned)__builtin_amdgcn_readlane((int)pl, (j + u) & 63);
                qv[u] = qq;
                const int sidx = min((int)(qq & 0xFFFFu), NN - 1);  // clamp garbage
                a[u] = nf[(size_t)sidx * DD + lane];
            }
#pragma unroll
            for (int u = 0; u < 16; ++u) {
                const float eb = emb_s[(((qv[u] >> 16) & 31) << 6) + lane];
                const float m  = fmaxf(a[u] + eb, 0.0f) + 1e-7f;
                float x = __expf(beta * m);
                x = (j + u < cn) ? x : 0.0f;   // mask tail slots
                den += x;
                num = fmaf(m, x, num);
            }
        }

        const float msg = (den > 0.0f) ? num / den : 0.0f;

        float ss = msg * msg;
        float fs = f * f;
#pragma unroll
        for (int m = 32; m >= 1; m >>= 1) {
            ss += __shfl_xor(ss, m, 64);
            fs += __shfl_xor(fs, m, 64);
        }

        const float feat =
            f + msg * (1.0f / fmaxf(sqrtf(ss), 1e-12f)) * sqrtf(fs) * scale;

        feat_s[w][lane] = feat;

        float acc = bias;
#pragma unroll
        for (int k = 0; k < 16; ++k) {
            const float4 fv = *(const float4*)&feat_s[w][4 * k];
            acc = fmaf(fv.x, wc[k].x, acc);
            acc = fmaf(fv.y, wc[k].y, acc);
            acc = fmaf(fv.z, wc[k].z, acc);
            acc = fmaf(fv.w, wc[k].w, acc);
        }
        if (node < NN)
            out[(size_t)node * DD + lane] = acc;

        pl = pl_n;
        cn = min(cn_n, DD);
        f  = f_n;
    }
}

extern "C" void kernel_launch(void* const* d_in, const int* in_sizes, int n_in,
                              void* d_out, int out_size, void* d_ws, size_t ws_size,
                              hipStream_t stream)
{
    const float* nf    = (const float*)d_in[0];
    const float* emb0  = (const float*)d_in[1];
    const float* emb1  = (const float*)d_in[2];
    const float* W     = (const float*)d_in[3];
    const float* b     = (const float*)d_in[4];
    const float* beta  = (const float*)d_in[5];
    const float* scale = (const float*)d_in[6];
    const int* src = (const int*)d_in[7];
    const int* dst = (const int*)d_in[8];
    const int* ef0 = (const int*)d_in[9];
    const int* ef1 = (const int*)d_in[10];

    int*            total   = (int*)d_ws;                    // 2048 ints
    float*          Wt      = (float*)(total + 2048);        // 4096 f32
    unsigned*       staging = (unsigned*)(Wt + 4096);        // KRF*SCAPF u32 (6.4MB)
    unsigned short* hist    = (unsigned short*)(staging + (size_t)KRF * SCAPF); // 1.91MB

    k_count<<<NBLK, 512, 0, stream>>>((const int4*)dst, hist, W, Wt);

    k_scan<<<(KRF + 255) / 256, 256, 0, stream>>>(hist, total);

    k_scatter<<<NBLK, 512, 0, stream>>>(
        (const int4*)src, (const int4*)dst, (const int4*)ef0, (const int4*)ef1,
        hist, staging);

    genconv_agg<<<KRF, 256, 0, stream>>>(
        nf, emb0, emb1, Wt, b, beta, scale, staging, total, (float*)d_out);
}

// Round 10
// 211.812 us; speedup vs baseline: 1.0927x; 1.0927x over previous
//
#include <hip/hip_runtime.h>

#define NN 50000
#define NE 1250000
#define DD 64
#define KRF 1563      // fine bins of 32 nodes (dst >> 5); 1563*32 = 50016
#define BSH 5         // log2 nodes per bin
#define SCAPF 1024    // staged-edge capacity per bin (mean 800, +8 sigma)
#define SCSHF 10      // log2(SCAPF)
#define CPAD 5        // counter padding: 1 counter per 32 ints = 128 B line

// ---------------------------------------------------------------------------
// ws layout: rcur[KRF<<CPAD] ints (200KB, 1 counter/128B line) | Wt[4096] f32
//            | staging[KRF*SCAPF] u32 (~6.4 MB)
// staging payload = src(16b) | (ef1*8+ef0)(5b)<<16 | (dst&31)(5b)<<21
// R13: R10 byte-exact EXCEPT allocation counters padded to one per 128B
// line. Fitted model across R5/R8/R9/R10: residual tracks allocation
// atomicAdds PER CACHE LINE (5-7K serialized L2 RMW round trips/line ->
// 70-110us) and was invariant because bins and lines scaled together.
// Padding cuts per-line depth to ~368 (one alloc per block per bin).
// ---------------------------------------------------------------------------

__global__ __launch_bounds__(512) void k_part(
    const int4* __restrict__ src4, const int4* __restrict__ dst4,
    const int4* __restrict__ ef04, const int4* __restrict__ ef14,
    const float* __restrict__ W, float* __restrict__ Wt,
    int* __restrict__ rcur, unsigned* __restrict__ staging)
{
    __shared__ int hist[KRF], rbase[KRF], cur[KRF];   // 18.8 KB
    const int t  = threadIdx.x;
    const int gb = blockIdx.x;

    for (int i = t; i < KRF; i += 512) { hist[i] = 0; cur[i] = 0; }
    if (gb == 0)   // piggyback W transpose
        for (int i = t; i < 4096; i += 512)
            Wt[(i & 63) * DD + (i >> 6)] = W[i];
    __syncthreads();

    unsigned pay[4];
    int rr[4];
#pragma unroll
    for (int u = 0; u < 4; ++u) rr[u] = -1;

    const int i4 = gb * 512 + t;
    if (i4 < NE / 4) {
        const int4 s  = src4[i4], d = dst4[i4];
        const int4 f0 = ef04[i4], f1 = ef14[i4];
        const int ds[4] = {d.x, d.y, d.z, d.w};
        const int ss[4] = {s.x, s.y, s.z, s.w};
        const int a0[4] = {f0.x, f0.y, f0.z, f0.w};
        const int a1[4] = {f1.x, f1.y, f1.z, f1.w};
#pragma unroll
        for (int u = 0; u < 4; ++u) {
            rr[u]  = ds[u] >> BSH;
            pay[u] = (unsigned)ss[u] | ((unsigned)(a1[u] * 8 + a0[u]) << 16)
                     | ((unsigned)(ds[u] & 31) << 21);
        }
    }
#pragma unroll
    for (int u = 0; u < 4; ++u)
        if (rr[u] >= 0) atomicAdd(&hist[rr[u]], 1);
    __syncthreads();

    for (int i = t; i < KRF; i += 512) {
        const int h = hist[i];
        if (h) rbase[i] = atomicAdd(&rcur[i << CPAD], h);   // padded counter
    }
    __syncthreads();

#pragma unroll
    for (int u = 0; u < 4; ++u) {
        if (rr[u] >= 0) {
            const int r   = rr[u];
            const int pos = rbase[r] + atomicAdd(&cur[r], 1);
            if (pos < SCAPF) staging[(r << SCSHF) + pos] = pay[u];
        }
    }
}

// ---------------------------------------------------------------------------
// Fused bucket + aggregation + MessageNorm + residual + GEMM.
// Block = 32 nodes = exactly one staging bin (zero scan redundancy).
// Byte-exact R10 structure (88.9us, VGPR 64).
// ---------------------------------------------------------------------------
__global__ __launch_bounds__(256, 4) void genconv_agg(
    const float* __restrict__ nf,
    const float* __restrict__ emb0, const float* __restrict__ emb1,
    const float* __restrict__ Wt,  const float* __restrict__ b,
    const float* __restrict__ beta_p, const float* __restrict__ scale_p,
    const unsigned* __restrict__ staging, const int* __restrict__ rcur,
    float* __restrict__ out)
{
    __shared__ float emb_s[32 * DD];      // 8 KB
    __shared__ float feat_s[4][DD];       // 1 KB
    __shared__ unsigned buck[32 * DD];    // 8 KB
    __shared__ int ldeg[32];

    const int t    = threadIdx.x;
    const int w    = t >> 6;
    const int lane = t & 63;
    const int bin  = blockIdx.x;
    const int base_node = bin << BSH;

    if (t < 32) ldeg[t] = 0;
    for (int i = t; i < 32 * DD; i += 256) {
        const int rr = i >> 6, c = i & 63;
        emb_s[i] = emb0[(rr & 7) * DD + c] + emb1[(rr >> 3) * DD + c];
    }

    float4 wc[16];
#pragma unroll
    for (int k = 0; k < 16; ++k)
        wc[k] = *(const float4*)(Wt + lane * DD + 4 * k);

    const float bias  = b[lane];
    const float beta  = beta_p[0];
    const float scale = scale_p[0];
    __syncthreads();

    // ---- Phase 1: bucket own segment's edges into per-node LDS lists ----
    const int ne = min(rcur[bin << CPAD], SCAPF);
    const unsigned* sg = staging + (bin << SCSHF);
    for (int i = t; i < ne; i += 256) {
        const unsigned p = sg[i];
        const int dl  = (p >> 21) & 31;
        const int pos = atomicAdd(&ldeg[dl], 1);
        if (pos < DD) buck[(dl << 6) + pos] = p & 0x1FFFFFu;
    }
    __syncthreads();

    // ---- Phase 2: 8 nodes per wave, proven scalar-gather loop ----
    const int nl0 = w << 3;
    unsigned pl = buck[(nl0 << 6) + lane];
    int cn = min(ldeg[nl0], DD);
    int node = base_node + nl0;
    float f = (node < NN) ? nf[(size_t)node * DD + lane] : 0.0f;

    for (int i = 0; i < 8; ++i) {
        const int nl = nl0 + i;
        node = base_node + nl;

        // prefetch next node's state (LDS payload + global feature)
        unsigned pl_n = 0u;
        int cn_n = 0;
        float f_n = 0.0f;
        if (i < 7) {
            pl_n = buck[((nl + 1) << 6) + lane];
            cn_n = ldeg[nl + 1];
            if (node + 1 < NN)
                f_n = nf[(size_t)(node + 1) * DD + lane];
        }

        float num = 0.0f, den = 0.0f;
        for (int j = 0; j < cn; j += 16) {
            float a[16];
            unsigned qv[16];
#pragma unroll
            for (int u = 0; u < 16; ++u) {
                const unsigned qq =
                    (unsigned)__builtin_amdgcn_readlane((int)pl, (j + u) & 63);
                qv[u] = qq;
                const int sidx = min((int)(qq & 0xFFFFu), NN - 1);  // clamp garbage
                a[u] = nf[(size_t)sidx * DD + lane];
            }
#pragma unroll
            for (int u = 0; u < 16; ++u) {
                const float eb = emb_s[(((qv[u] >> 16) & 31) << 6) + lane];
                const float m  = fmaxf(a[u] + eb, 0.0f) + 1e-7f;
                float x = __expf(beta * m);
                x = (j + u < cn) ? x : 0.0f;   // mask tail slots
                den += x;
                num = fmaf(m, x, num);
            }
        }

        const float msg = (den > 0.0f) ? num / den : 0.0f;

        float ss = msg * msg;
        float fs = f * f;
#pragma unroll
        for (int m = 32; m >= 1; m >>= 1) {
            ss += __shfl_xor(ss, m, 64);
            fs += __shfl_xor(fs, m, 64);
        }

        const float feat =
            f + msg * (1.0f / fmaxf(sqrtf(ss), 1e-12f)) * sqrtf(fs) * scale;

        feat_s[w][lane] = feat;

        float acc = bias;
#pragma unroll
        for (int k = 0; k < 16; ++k) {
            const float4 fv = *(const float4*)&feat_s[w][4 * k];
            acc = fmaf(fv.x, wc[k].x, acc);
            acc = fmaf(fv.y, wc[k].y, acc);
            acc = fmaf(fv.z, wc[k].z, acc);
            acc = fmaf(fv.w, wc[k].w, acc);
        }
        if (node < NN)
            out[(size_t)node * DD + lane] = acc;

        pl = pl_n;
        cn = min(cn_n, DD);
        f  = f_n;
    }
}

extern "C" void kernel_launch(void* const* d_in, const int* in_sizes, int n_in,
                              void* d_out, int out_size, void* d_ws, size_t ws_size,
                              hipStream_t stream)
{
    const float* nf    = (const float*)d_in[0];
    const float* emb0  = (const float*)d_in[1];
    const float* emb1  = (const float*)d_in[2];
    const float* W     = (const float*)d_in[3];
    const float* b     = (const float*)d_in[4];
    const float* beta  = (const float*)d_in[5];
    const float* scale = (const float*)d_in[6];
    const int* src = (const int*)d_in[7];
    const int* dst = (const int*)d_in[8];
    const int* ef0 = (const int*)d_in[9];
    const int* ef1 = (const int*)d_in[10];

    int*      rcur    = (int*)d_ws;                       // KRF<<CPAD ints (200KB)
    float*    Wt      = (float*)(rcur + (KRF << CPAD));   // 4096 f32
    unsigned* staging = (unsigned*)(Wt + 4096);           // KRF*SCAPF u32 (~6.4MB)

    hipMemsetAsync(rcur, 0, (size_t)(KRF << CPAD) * sizeof(int), stream);

    k_part<<<(NE / 4 + 511) / 512, 512, 0, stream>>>(
        (const int4*)src, (const int4*)dst, (const int4*)ef0, (const int4*)ef1,
        W, Wt, rcur, staging);

    genconv_agg<<<KRF, 256, 0, stream>>>(
        nf, emb0, emb1, Wt, b, beta, scale, staging, rcur, (float*)d_out);
}